// Round 9
// baseline (98.286 us; speedup 1.0000x reference)
//
#include <hip/hip_runtime.h>

#define SEQ   2048
#define HALF  1024          // tokens gathered per block (2 blocks/row)
#define EMB   100
#define BOT   5
#define HSIZE 4096          // power of two, 2*SEQ slots, <=50% load factor
#define FT    1024          // threads per block (16 waves)
#define NW    16
#define GW    12            // pure-gather waves
#define GTOK  76            // tokens per pure-gather wave
#define HTOK  28            // tokens per histogram wave   (12*76 + 4*28 = 1024)

// ---------------- kA: overlapped histogram + two-pass gather ----------------
// Two blocks per row. Math: cnt*idf = idf + (cnt-1)*idf, so pass-1 gathers with
// weight idf[k] (NO histogram dependency) while waves 12..15 concurrently build
// the full-row LDS hash histogram. Pass-2 adds the rare (cnt-1)*idf corrections
// (~41 tokens/block, rows cache-hot). 1/Z is deferred to kB (zhalf written per
// block). Determinism: fixed wave->token partition, fixed reduce orders,
// race-invariant integer counts, lane-ordered ballot fixup. No device fences.
__global__ __launch_bounds__(FT) void kA_fused(
    const int* __restrict__ x, const float* __restrict__ idf,
    const float* __restrict__ we, float* __restrict__ partial,
    float* __restrict__ zhalf)
{
    __shared__ int   hkey[HSIZE];
    __shared__ int   hcnt[HSIZE];
    __shared__ int   skey[SEQ];
    __shared__ float sdup[HALF];         // (cnt-1)*idf per half-token (mostly 0)
    __shared__ float part[NW][EMB];
    __shared__ float zred[NW];

    const int bx   = blockIdx.x;
    const int b    = bx >> 1;
    const int half = bx & 1;
    const int tid  = threadIdx.x;
    const int lane = tid & 63, wid = tid >> 6;
    const int vl   = (lane < EMB / 2) ? lane : 0;   // lanes 50..63 alias lane 0

    for (int i = tid; i < HSIZE; i += FT) { hkey[i] = -1; hcnt[i] = 0; }
    for (int i = tid; i < SEQ; i += FT) skey[i] = x[(size_t)b * SEQ + i];
    __syncthreads();

    // ---- waves 12..15: full-row histogram (overlaps pass-1 below) ----
    if (wid >= GW) {
        const int ht = tid - GW * 64;               // 0..255
        for (int i = ht; i < SEQ; i += (NW - GW) * 64) {
            int key = skey[i];
            unsigned slot = ((unsigned)key * 2654435761u) >> 20;
            for (;;) {
                int prev = atomicCAS(&hkey[slot], -1, key);
                if (prev == -1 || prev == key) { atomicAdd(&hcnt[slot], 1); break; }
                slot = (slot + 1) & (HSIZE - 1);
            }
        }
    }

    // ---- pass-1 gather (ALL waves): weight = idf[key]; per-wave Z ----
    const int hb    = half * HALF;
    const int start = (wid < GW) ? wid * GTOK : GW * GTOK + (wid - GW) * HTOK;
    const int end   = start + ((wid < GW) ? GTOK : HTOK);

    float accx, accy;
    float z = 0.0f;
    {
        float2 a0={0,0},a1={0,0},a2={0,0},a3={0,0},a4={0,0},a5={0,0},a6={0,0},a7={0,0};
        int i = start;
        for (; i + 8 <= end; i += 8) {
            int   k0=skey[hb+i+0], k1=skey[hb+i+1], k2=skey[hb+i+2], k3=skey[hb+i+3];
            int   k4=skey[hb+i+4], k5=skey[hb+i+5], k6=skey[hb+i+6], k7=skey[hb+i+7];
            float w0=idf[k0], w1=idf[k1], w2=idf[k2], w3=idf[k3];
            float w4=idf[k4], w5=idf[k5], w6=idf[k6], w7=idf[k7];
            float2 v0=((const float2*)(we+(size_t)k0*EMB))[vl];
            float2 v1=((const float2*)(we+(size_t)k1*EMB))[vl];
            float2 v2=((const float2*)(we+(size_t)k2*EMB))[vl];
            float2 v3=((const float2*)(we+(size_t)k3*EMB))[vl];
            float2 v4=((const float2*)(we+(size_t)k4*EMB))[vl];
            float2 v5=((const float2*)(we+(size_t)k5*EMB))[vl];
            float2 v6=((const float2*)(we+(size_t)k6*EMB))[vl];
            float2 v7=((const float2*)(we+(size_t)k7*EMB))[vl];
            a0.x+=w0*v0.x; a0.y+=w0*v0.y;  a1.x+=w1*v1.x; a1.y+=w1*v1.y;
            a2.x+=w2*v2.x; a2.y+=w2*v2.y;  a3.x+=w3*v3.x; a3.y+=w3*v3.y;
            a4.x+=w4*v4.x; a4.y+=w4*v4.y;  a5.x+=w5*v5.x; a5.y+=w5*v5.y;
            a6.x+=w6*v6.x; a6.y+=w6*v6.y;  a7.x+=w7*v7.x; a7.y+=w7*v7.y;
            z += ((w0+w1)+(w2+w3)) + ((w4+w5)+(w6+w7));
        }
        for (; i < end; ++i) {
            int k = skey[hb+i];
            float w = idf[k];
            float2 v = ((const float2*)(we+(size_t)k*EMB))[vl];
            a0.x += w*v.x; a0.y += w*v.y; z += w;
        }
        accx = ((a0.x+a1.x)+(a2.x+a3.x)) + ((a4.x+a5.x)+(a6.x+a7.x));
        accy = ((a0.y+a1.y)+(a2.y+a3.y)) + ((a4.y+a5.y)+(a6.y+a7.y));
    }
    if (lane == 0) zred[wid] = z;       // idf loads are wave-uniform -> z identical per lane
    __syncthreads();                    // histogram complete; counts final

    // ---- duplicate weights for this half's tokens (FT == HALF: one each) ----
    {
        int k = skey[hb + tid];
        unsigned slot = ((unsigned)k * 2654435761u) >> 20;
        while (hkey[slot] != k) slot = (slot + 1) & (HSIZE - 1);
        int c = hcnt[slot];
        sdup[tid] = (c > 1) ? (float)(c - 1) * idf[k] : 0.0f;
    }
    __syncthreads();

    // ---- pass-2: wave w fixes tokens [w*64, w*64+64); ~2-3 hits per wave ----
    {
        float wl = sdup[wid * 64 + lane];
        int   kl = skey[hb + wid * 64 + lane];
        unsigned long long m = __ballot(wl != 0.0f);
        while (m) {
            int src = __ffsll((long long)m) - 1;  m &= m - 1;   // lane order: fixed
            float w = __shfl(wl, src);
            int   k = __shfl(kl, src);
            float2 v = ((const float2*)(we + (size_t)k * EMB))[vl];
            accx += w * v.x; accy += w * v.y;
        }
    }
    if (lane < EMB / 2) { part[wid][2*lane] = accx; part[wid][2*lane+1] = accy; }
    __syncthreads();

    if (tid < EMB) {
        float a = 0.0f;
        #pragma unroll
        for (int w = 0; w < NW; ++w) a += part[w][tid];   // fixed order
        partial[(size_t)bx * EMB + tid] = a;
    }
    if (tid == 0) {
        float t = 0.0f;
        #pragma unroll
        for (int w = 0; w < NW; ++w) t += zred[w];        // fixed order
        zhalf[bx] = t;
    }
}

// ---------------- kB: combine halves, apply 1/Z, tiny MLP ----------------
__global__ __launch_bounds__(128) void kB_mlp(
    const float* __restrict__ partial, const float* __restrict__ zhalf,
    const float* __restrict__ fc1w, const float* __restrict__ fc1b,
    const float* __restrict__ fc2w, const float* __restrict__ fc2b,
    float* __restrict__ out)
{
    __shared__ float doc[EMB];
    __shared__ float hsh[BOT];

    const int b = blockIdx.x, tid = threadIdx.x;
    const float iz = 1.0f / (zhalf[2*b] + zhalf[2*b+1]);   // fixed order

    if (tid < EMB) {
        const float* p = partial + (size_t)b * 2 * EMB + tid;
        doc[tid] = (p[0] + p[EMB]) * iz;                   // fixed order
    }
    __syncthreads();

    if (tid < BOT) {
        float h = fc1b[tid];
        const float* wr = fc1w + tid * EMB;
        for (int e = 0; e < EMB; ++e) h += doc[e] * wr[e];
        hsh[tid] = h;
    }
    __syncthreads();

    if (tid < EMB) {
        float o = fc2b[tid];
        const float* wr = fc2w + tid * BOT;
        #pragma unroll
        for (int j = 0; j < BOT; ++j) o += hsh[j] * wr[j];
        out[(size_t)b * EMB + tid] = o;
    }
}

extern "C" void kernel_launch(void* const* d_in, const int* in_sizes, int n_in,
                              void* d_out, int out_size, void* d_ws, size_t ws_size,
                              hipStream_t stream) {
    const int*   x    = (const int*)d_in[0];
    const float* we   = (const float*)d_in[1];
    const float* idf  = (const float*)d_in[2];
    const float* fc1w = (const float*)d_in[3];
    const float* fc1b = (const float*)d_in[4];
    const float* fc2w = (const float*)d_in[5];
    const float* fc2b = (const float*)d_in[6];
    float*       out  = (float*)d_out;

    const int B = in_sizes[0] / SEQ;  // 128

    char*  ws      = (char*)d_ws;
    float* zhalf   = (float*)ws;                 // B*2 floats
    float* partial = (float*)(ws + 4096);        // B*2*EMB floats (~102 KB)

    kA_fused<<<B * 2, FT,  0, stream>>>(x, idf, we, partial, zhalf);
    kB_mlp  <<<B,     128, 0, stream>>>(partial, zhalf, fc1w, fc1b, fc2w, fc2b, out);
}